// Round 3
// baseline (179.921 us; speedup 1.0000x reference)
//
#include <hip/hip_runtime.h>
#include <hip/hip_bf16.h>
#include <stdint.h>

#define NB 8
#define TT 2048
#define DD 1024
#define HDIM 64

typedef __bf16 bf16x8 __attribute__((ext_vector_type(8)));
typedef float f32x4 __attribute__((ext_vector_type(4)));

static_assert(sizeof(bf16x8) == 16, "bf16x8 must be 16 bytes");

__device__ inline ushort f2bf_bits(float f) {
    __hip_bfloat16 h = __float2bfloat16(f);
    return *reinterpret_cast<ushort*>(&h);
}
__device__ inline float bfbits2f(ushort u) {
    unsigned v = ((unsigned)u) << 16;
    return __builtin_bit_cast(float, v);
}
__device__ inline bf16x8 ldb8(const ushort* p) {
    return *reinterpret_cast<const bf16x8*>(p);
}

// async global->LDS DMA, 16B/lane: dest = wave-uniform base + lane*16.
typedef __attribute__((address_space(3))) uint32_t lds_u32;
typedef const __attribute__((address_space(1))) uint32_t glb_u32;
__device__ inline void gl_lds16(const void* g, void* l) {
    __builtin_amdgcn_global_load_lds((glb_u32*)g, (lds_u32*)l, 16, 0, 0);
}

// s_waitcnt immediates (gfx9: vm[3:0]+[15:14], exp[6:4], lgkm[11:8])
#define WCNT_VM3   0xF73   // vmcnt(3)
#define WCNT_VM4   0xF74   // vmcnt(4)
#define WCNT_LGKM0 0xC07F  // lgkmcnt(0), vmcnt/expcnt unconstrained

// ---------------------------------------------------------------------------
// Inline dtype probe: f32 x -> even halfwords show wild bf16 exponents.
// ---------------------------------------------------------------------------
__device__ inline int probe_f32(const ushort* x) {
    int lane = threadIdx.x & 63;
    int wild = 0;
    #pragma unroll
    for (int j = 0; j < 4; ++j) {
        ushort u = x[(lane * 4 + j) * 32];
        int e = (u >> 7) & 0xFF;
        wild += (e >= 0xC0);
    }
    unsigned long long m = __ballot(wild > 0);
    return __popcll(m) > 8;
}

// ---------------------------------------------------------------------------
// Kernel 1: pack weights -> Wt[192][1024] bf16 (row = global out-col, k
// contiguous).  Softmax scale * log2(e) folded into Wq (exp2 domain).
// ---------------------------------------------------------------------------
__global__ __launch_bounds__(256) void k_wt(const ushort* __restrict__ x,
                                            const void* __restrict__ Wq,
                                            const void* __restrict__ Wk,
                                            const void* __restrict__ Wv,
                                            ushort* __restrict__ Wt) {
    int f32m = probe_f32(x);
    int idx = blockIdx.x * 256 + threadIdx.x;   // 0 .. 196607
    int mat = idx >> 16;
    int rem = idx & 65535;                      // = d*64 + h
    int d = rem >> 6;
    int h = rem & 63;
    const void* W = (mat == 0) ? Wq : (mat == 1) ? Wk : Wv;
    float v;
    if (f32m) v = ((const float*)W)[rem];
    else      v = bfbits2f(((const ushort*)W)[rem]);
    if (mat == 0) v *= 0.18033688011112042f;    // 0.125 * log2(e)
    Wt[(size_t)mat * 65536 + (size_t)h * DD + d] = f2bf_bits(v);
}

// ---------------------------------------------------------------------------
// Kernel 2: QKV projection (round-0 known-good structure, ~45us).
// 512 blocks x 512 threads (8 waves); block = 32 rows x ALL 192 cols.
// Wave = 16 rows (mt=w>>2) x 48 cols (nh=w&3), 3 accs.  BK=64
// double-buffered LDS DMA (48KB B + 16KB A = 64KB -> 2 blocks/CU =
// 16 waves/CU), vmcnt crossing raw s_barrier.
// ---------------------------------------------------------------------------
template <int F32M>
__device__ inline void proj_body(const void* __restrict__ xv,
                                 const ushort* __restrict__ Wt,
                                 ushort* __restrict__ Qw,
                                 ushort* __restrict__ Kw,
                                 ushort* __restrict__ Vtw,
                                 ushort* Bf, float* Af) {
    int tid  = threadIdx.x;
    int w    = tid >> 6;                 // 0..7
    int lane = tid & 63;
    int quad = lane >> 4;
    int col  = lane & 15;
    int mt   = w >> 2;                   // m-tile 0..1
    int nh   = w & 3;                    // n-strip 0..3 (48 cols)
    int m0   = blockIdx.x * 32;

    ushort* Afb = (ushort*)Af;           // bf16 path aliases the A buffer

    auto stage = [&](int buf, int kkk) {
        #pragma unroll
        for (int j = 0; j < 3; ++j) {
            int f  = w * 3 + j;          // 0..23 = nt*2+ks
            int nt = f >> 1, ks = f & 1;
            gl_lds16(Wt + (size_t)(nt * 16 + col) * DD + kkk + ks * 32 + quad * 8,
                     Bf + ((size_t)buf * 24 + f) * 512);
        }
        if (F32M) {
            int amt = w >> 2, ks = (w >> 1) & 1, hf = w & 1;   // 8 frags, 1/wave
            gl_lds16((const float*)xv + (size_t)(m0 + amt * 16 + col) * DD
                         + kkk + ks * 32 + hf * 4 + quad * 8,
                     Af + ((((buf * 2 + amt) * 2 + ks) * 2) + hf) * 256);
        } else if (w < 4) {
            int amt = w >> 1, ks = w & 1;                      // 4 frags, waves 0-3
            gl_lds16((const ushort*)xv + (size_t)(m0 + amt * 16 + col) * DD
                         + kkk + ks * 32 + quad * 8,
                     Afb + (((buf * 2 + amt) * 2) + ks) * 512);
        }
    };

    f32x4 acc[3];
    #pragma unroll
    for (int i = 0; i < 3; ++i) acc[i] = (f32x4){0.f,0.f,0.f,0.f};

    stage(0, 0);
    for (int kk = 0; kk < DD; kk += 64) {
        int p  = (kk >> 6) & 1;
        int kn = (kk + 64 < DD) ? kk + 64 : kk;
        stage(p ^ 1, kn);
        if (F32M) {
            __builtin_amdgcn_s_waitcnt(WCNT_VM4);   // own 4 chunk-k DMAs done
        } else {
            if (w < 4) __builtin_amdgcn_s_waitcnt(WCNT_VM4);
            else       __builtin_amdgcn_s_waitcnt(WCNT_VM3);
        }
        __builtin_amdgcn_s_barrier();

        #pragma unroll
        for (int ks = 0; ks < 2; ++ks) {
            bf16x8 a;
            if (F32M) {
                f32x4 alo = *reinterpret_cast<const f32x4*>(Af + ((((p * 2 + mt) * 2 + ks) * 2) + 0) * 256 + lane * 4);
                f32x4 ahi = *reinterpret_cast<const f32x4*>(Af + ((((p * 2 + mt) * 2 + ks) * 2) + 1) * 256 + lane * 4);
                #pragma unroll
                for (int j = 0; j < 4; ++j) { a[j] = (__bf16)alo[j]; a[4+j] = (__bf16)ahi[j]; }
            } else {
                a = ldb8(Afb + (((p * 2 + mt) * 2) + ks) * 512 + lane * 8);
            }
            #pragma unroll
            for (int j = 0; j < 3; ++j) {
                int nt = nh * 3 + j;
                bf16x8 b = ldb8(Bf + ((size_t)p * 24 + nt * 2 + ks) * 512 + lane * 8);
                acc[j] = __builtin_amdgcn_mfma_f32_16x16x32_bf16(a, b, acc[j], 0, 0, 0);
            }
        }
        __builtin_amdgcn_s_waitcnt(WCNT_LGKM0);   // buf[p] reads complete
        __builtin_amdgcn_s_barrier();             // before buf[p] re-stage
    }

    // C/D layout: row = quad*4 + reg, col = lane&15
    #pragma unroll
    for (int j = 0; j < 3; ++j) {
        int nt  = nh * 3 + j;
        int mat = nt >> 2;                 // 0=Q,1=K,2=V
        int h   = (nt & 3) * 16 + col;
        if (mat == 2) {
            #pragma unroll
            for (int r = 0; r < 4; ++r) {
                int row = m0 + mt * 16 + quad * 4 + r;
                int bb = row >> 11;
                int t  = row & (TT - 1);
                Vtw[(size_t)bb * HDIM * TT + (size_t)h * TT + t] = f2bf_bits(acc[j][r]);
            }
        } else {
            ushort* outp = (mat == 0) ? Qw : Kw;
            #pragma unroll
            for (int r = 0; r < 4; ++r) {
                int row = m0 + mt * 16 + quad * 4 + r;
                outp[(size_t)row * HDIM + h] = f2bf_bits(acc[j][r]);
            }
        }
    }
}

__global__ __launch_bounds__(512) void k_proj(const void* __restrict__ xv,
                                              const ushort* __restrict__ Wt,
                                              ushort* __restrict__ Qw,
                                              ushort* __restrict__ Kw,
                                              ushort* __restrict__ Vtw) {
    __shared__ ushort Bf[2 * 24 * 512];        // 48 KB
    __shared__ float  Af[2 * 2 * 2 * 2 * 256]; // 16 KB (bf16 path aliases)
    if (probe_f32((const ushort*)xv)) proj_body<1>(xv, Wt, Qw, Kw, Vtw, Bf, Af);
    else                              proj_body<0>(xv, Wt, Qw, Kw, Vtw, Bf, Af);
}

// ---------------------------------------------------------------------------
// Kernel 3: split-K causal flash attention, BARRIER-FREE.
// K/V (4 MB total bf16) is L2-resident -> LDS staging was pure overhead
// (guide m169).  Each wave is fully independent: one (b, q-tile, chunk),
// K/V fragments loaded straight global->VGPR (L2 hits), V loads issued
// before the exp chain so latency hides under QK+softmax.  Per-wave causal
// loop bound (no block-uniform convoy).  LDS = 5 KB P-transpose only
// (wave-private; per-wave DS ops are in-order -> no sync needed).
// ---------------------------------------------------------------------------
__global__ __launch_bounds__(256) void k_attn(const ushort* __restrict__ Qw,
                                              const ushort* __restrict__ Kw,
                                              const ushort* __restrict__ Vtw,
                                              ushort* __restrict__ Po,
                                              float* __restrict__ Pl) {
    int w    = threadIdx.x >> 6;
    int lane = threadIdx.x & 63;
    int quad = lane >> 4;
    int col  = lane & 15;
    int bid  = blockIdx.x;               // 0..639
    int b    = bid & 7;
    int idx  = 79 - (bid >> 3);          // longer blocks earlier-ish
    int c, g;
    if (idx < 32)      { c = 0; g = idx; }
    else if (idx < 56) { c = 1; g = idx - 24; }
    else if (idx < 72) { c = 2; g = idx - 40; }
    else               { c = 3; g = idx - 48; }
    int qb = 4 * g + w;                  // this wave's q-tile
    int m0 = qb * 16;
    int Bq = (qb < 32) ? qb : (qb < 64) ? 2*qb - 32 : (qb < 96) ? 3*qb - 96 : 4*qb - 192;
    int pid = b * 320 + Bq + c;

    const ushort* Qb = Qw + (size_t)b * TT * HDIM;
    const ushort* Kb = Kw + (size_t)b * TT * HDIM;
    const ushort* Vb = Vtw + (size_t)b * HDIM * TT;

    __shared__ ushort Pls[4][16][40];    // 5 KB per-wave P roundtrip

    bf16x8 qf0 = ldb8(Qb + (size_t)(m0 + col) * HDIM + quad * 8);
    bf16x8 qf1 = ldb8(Qb + (size_t)(m0 + col) * HDIM + 32 + quad * 8);

    f32x4 o0 = {0.f,0.f,0.f,0.f};
    f32x4 o1 = {0.f,0.f,0.f,0.f};
    f32x4 o2 = {0.f,0.f,0.f,0.f};
    f32x4 o3 = {0.f,0.f,0.f,0.f};
    float rsum[4] = {0.f, 0.f, 0.f, 0.f};

    const int start = c * 512;
    const int nst   = (min(start + 512, m0 + 16) - start + 31) >> 5;  // per-wave

    for (int t = 0; t < nst; ++t) {
        int s0 = start + t * 32;

        // K fragments: rows s0..s0+31, each wave's lane (col,quad) grabs 16B
        const ushort* kp = Kb + (size_t)(s0 + col) * HDIM + quad * 8;
        bf16x8 ck0l = ldb8(kp);
        bf16x8 ck0h = ldb8(kp + 32);
        bf16x8 ck1l = ldb8(kp + (size_t)16 * HDIM);
        bf16x8 ck1h = ldb8(kp + (size_t)16 * HDIM + 32);

        // V fragments issued early: latency hides under QK MFMA + exp chain
        const ushort* vp = Vb + (size_t)col * TT + s0 + quad * 8;
        bf16x8 cv0 = ldb8(vp);
        bf16x8 cv1 = ldb8(vp + (size_t)16 * TT);
        bf16x8 cv2 = ldb8(vp + (size_t)32 * TT);
        bf16x8 cv3 = ldb8(vp + (size_t)48 * TT);

        f32x4 S0 = {0.f,0.f,0.f,0.f};
        f32x4 S1 = {0.f,0.f,0.f,0.f};
        S0 = __builtin_amdgcn_mfma_f32_16x16x32_bf16(qf0, ck0l, S0, 0, 0, 0);
        S0 = __builtin_amdgcn_mfma_f32_16x16x32_bf16(qf1, ck0h, S0, 0, 0, 0);
        S1 = __builtin_amdgcn_mfma_f32_16x16x32_bf16(qf0, ck1l, S1, 0, 0, 0);
        S1 = __builtin_amdgcn_mfma_f32_16x16x32_bf16(qf1, ck1h, S1, 0, 0, 0);

        #pragma unroll
        for (int r = 0; r < 4; ++r) {
            int trow = m0 + quad * 4 + r;
            float aa = (s0 + col      > trow) ? -1e30f : S0[r];
            float dd = (s0 + 16 + col > trow) ? -1e30f : S1[r];
            float p0 = exp2f(aa);
            float p1 = exp2f(dd);
            rsum[r] += p0 + p1;
            Pls[w][quad * 4 + r][col]      = f2bf_bits(p0);
            Pls[w][quad * 4 + r][16 + col] = f2bf_bits(p1);
        }
        bf16x8 pf = ldb8(&Pls[w][col][quad * 8]);

        o0 = __builtin_amdgcn_mfma_f32_16x16x32_bf16(pf, cv0, o0, 0, 0, 0);
        o1 = __builtin_amdgcn_mfma_f32_16x16x32_bf16(pf, cv1, o1, 0, 0, 0);
        o2 = __builtin_amdgcn_mfma_f32_16x16x32_bf16(pf, cv2, o2, 0, 0, 0);
        o3 = __builtin_amdgcn_mfma_f32_16x16x32_bf16(pf, cv3, o3, 0, 0, 0);
    }

    #pragma unroll
    for (int off = 1; off < 16; off <<= 1) {
        #pragma unroll
        for (int r = 0; r < 4; ++r)
            rsum[r] += __shfl_xor(rsum[r], off, 64);
    }

    ushort* pb = Po + (size_t)pid * 1024;
    #pragma unroll
    for (int r = 0; r < 4; ++r) {
        int row = quad * 4 + r;
        pb[row * 64 + 0*16 + col] = f2bf_bits(o0[r]);
        pb[row * 64 + 1*16 + col] = f2bf_bits(o1[r]);
        pb[row * 64 + 2*16 + col] = f2bf_bits(o2[r]);
        pb[row * 64 + 3*16 + col] = f2bf_bits(o3[r]);
        if (col == 0) Pl[pid * 16 + row] = rsum[r];
    }
}

// ---------------------------------------------------------------------------
// Kernel 4: merge <=4 chunk partials (plain sum, shared implicit max=0),
// normalize by total L, store out.  One wave per (b,qb).
// ---------------------------------------------------------------------------
__global__ __launch_bounds__(256) void k_merge(const ushort* __restrict__ x,
                                               const ushort* __restrict__ Po,
                                               const float* __restrict__ Pl,
                                               void* __restrict__ outv) {
    int f32m = probe_f32(x);
    int wid  = blockIdx.x * 4 + (threadIdx.x >> 6);  // 0..1023
    int lane = threadIdx.x & 63;
    int row  = lane >> 2;
    int g    = lane & 3;
    int b    = wid >> 7;
    int qb   = wid & 127;
    int nch  = (qb >> 5) + 1;
    int Bq   = (qb < 32) ? qb : (qb < 64) ? 2*qb - 32 : (qb < 96) ? 3*qb - 96 : 4*qb - 192;
    int pid0 = b * 320 + Bq;

    float L = 0.f;
    #pragma unroll
    for (int c = 0; c < 4; ++c)
        if (c < nch) L += Pl[(pid0 + c) * 16 + row];
    float inv = 1.0f / L;

    float o[16];
    #pragma unroll
    for (int j = 0; j < 16; ++j) o[j] = 0.f;
    #pragma unroll
    for (int c = 0; c < 4; ++c) {
        if (c < nch) {
            const ushort* p = Po + (size_t)(pid0 + c) * 1024 + row * 64 + g * 16;
            bf16x8 v0 = ldb8(p);
            bf16x8 v1 = ldb8(p + 8);
            #pragma unroll
            for (int j = 0; j < 8; ++j) {
                o[j]     += (float)v0[j];
                o[8 + j] += (float)v1[j];
            }
        }
    }

    size_t obase = ((size_t)b * TT + qb * 16 + row) * HDIM + g * 16;
    if (f32m) {
        float* ob = (float*)outv + obase;
        #pragma unroll
        for (int j = 0; j < 16; ++j) ob[j] = o[j] * inv;
    } else {
        ushort* ob = (ushort*)outv + obase;
        #pragma unroll
        for (int j = 0; j < 16; ++j) ob[j] = f2bf_bits(o[j] * inv);
    }
}

// ---------------------------------------------------------------------------
extern "C" void kernel_launch(void* const* d_in, const int* in_sizes, int n_in,
                              void* d_out, int out_size, void* d_ws, size_t ws_size,
                              hipStream_t stream) {
    const ushort* x = (const ushort*)d_in[0];
    ushort* Wt  = (ushort*)d_ws;                       // 196608 elts
    ushort* Qw  = Wt + 3 * HDIM * DD;
    ushort* Kw  = Qw + (size_t)NB * TT * HDIM;
    ushort* Vtw = Kw + (size_t)NB * TT * HDIM;
    ushort* Po  = Vtw + (size_t)NB * TT * HDIM;        // 2560*1024 ushorts
    float*  Pl  = (float*)(Po + (size_t)2560 * 1024);  // ~12.2 MB total

    k_wt   <<<768, 256, 0, stream>>>(x, d_in[1], d_in[2], d_in[3], Wt);
    k_proj <<<512, 512, 0, stream>>>(d_in[0], Wt, Qw, Kw, Vtw);
    k_attn <<<640, 256, 0, stream>>>(Qw, Kw, Vtw, Po, Pl);
    k_merge<<<256, 256, 0, stream>>>(x, Po, Pl, d_out);
}

// Round 5
// 153.327 us; speedup vs baseline: 1.1734x; 1.1734x over previous
//
#include <hip/hip_runtime.h>
#include <hip/hip_bf16.h>
#include <stdint.h>

#define NB 8
#define TT 2048
#define DD 1024
#define HDIM 64

typedef __bf16 bf16x8 __attribute__((ext_vector_type(8)));
typedef float f32x4 __attribute__((ext_vector_type(4)));

static_assert(sizeof(bf16x8) == 16, "bf16x8 must be 16 bytes");

__device__ inline ushort f2bf_bits(float f) {
    __hip_bfloat16 h = __float2bfloat16(f);
    return *reinterpret_cast<ushort*>(&h);
}
__device__ inline float bfbits2f(ushort u) {
    unsigned v = ((unsigned)u) << 16;
    return __builtin_bit_cast(float, v);
}
__device__ inline bf16x8 ldb8(const ushort* p) {
    return *reinterpret_cast<const bf16x8*>(p);
}

// async global->LDS DMA, 16B/lane: dest = wave-uniform base + lane*16.
typedef __attribute__((address_space(3))) uint32_t lds_u32;
typedef const __attribute__((address_space(1))) uint32_t glb_u32;
__device__ inline void gl_lds16(const void* g, void* l) {
    __builtin_amdgcn_global_load_lds((glb_u32*)g, (lds_u32*)l, 16, 0, 0);
}

// s_waitcnt immediates (gfx9: vm[3:0]+[15:14], exp[6:4], lgkm[11:8])
#define WCNT_VM2   0xF72   // vmcnt(2)
#define WCNT_VM4   0xF74   // vmcnt(4)
#define WCNT_VM6   0xF76   // vmcnt(6)
#define WCNT_LGKM0 0xC07F  // lgkmcnt(0), vmcnt/expcnt unconstrained

// ---------------------------------------------------------------------------
// Inline dtype probe: f32 x -> even halfwords show wild bf16 exponents.
// ---------------------------------------------------------------------------
__device__ inline int probe_f32(const ushort* x) {
    int lane = threadIdx.x & 63;
    int wild = 0;
    #pragma unroll
    for (int j = 0; j < 4; ++j) {
        ushort u = x[(lane * 4 + j) * 32];
        int e = (u >> 7) & 0xFF;
        wild += (e >= 0xC0);
    }
    unsigned long long m = __ballot(wild > 0);
    return __popcll(m) > 8;
}

// ---------------------------------------------------------------------------
// Kernel 1: pack weights -> Wt[192][1024] bf16 (row = global out-col, k
// contiguous).  Softmax scale * log2(e) folded into Wq (exp2 domain).
// ---------------------------------------------------------------------------
__global__ __launch_bounds__(256) void k_wt(const ushort* __restrict__ x,
                                            const void* __restrict__ Wq,
                                            const void* __restrict__ Wk,
                                            const void* __restrict__ Wv,
                                            ushort* __restrict__ Wt) {
    int f32m = probe_f32(x);
    int idx = blockIdx.x * 256 + threadIdx.x;   // 0 .. 196607
    int mat = idx >> 16;
    int rem = idx & 65535;                      // = d*64 + h
    int d = rem >> 6;
    int h = rem & 63;
    const void* W = (mat == 0) ? Wq : (mat == 1) ? Wk : Wv;
    float v;
    if (f32m) v = ((const float*)W)[rem];
    else      v = bfbits2f(((const ushort*)W)[rem]);
    if (mat == 0) v *= 0.18033688011112042f;    // 0.125 * log2(e)
    Wt[(size_t)mat * 65536 + (size_t)h * DD + d] = f2bf_bits(v);
}

// ---------------------------------------------------------------------------
// Kernel 2: QKV projection, M=64 blocks to HALVE redundant B staging.
// 256 blocks x 1024 threads (16 waves = 4 mt x 4 nh); block = 64 rows x
// ALL 192 cols.  Wave = 16 rows x 48 cols, 3 accs, 6 MFMA/step.
// B traffic 196->98 MB.  TRIPLE-buffered depth-2 staging, counted vmcnt
// = 2 x own-DMAs-per-stage so stages t+1,t+2 stay in flight.
// f32: waves 0-7 {2B+1A, vmcnt(6)}, waves 8-15 {1B+1A(a=w), vmcnt(4)}.
// bf16: waves 0-11 {2B}, waves 12-15 {2A}, all vmcnt(4).  LDS 120 KB.
// (Round-4 crash was A-frag index 8..23 OOB; now a=w in [8,16).)
// ---------------------------------------------------------------------------
template <int F32M>
__device__ inline void proj_body(const void* __restrict__ xv,
                                 const ushort* __restrict__ Wt,
                                 ushort* __restrict__ Qw,
                                 ushort* __restrict__ Kw,
                                 ushort* __restrict__ Vtw,
                                 ushort* Bf, float* Af) {
    int tid  = threadIdx.x;
    int w    = tid >> 6;                 // 0..15
    int lane = tid & 63;
    int quad = lane >> 4;
    int col  = lane & 15;
    int mt   = w >> 2;                   // m-tile 0..3
    int nh   = w & 3;                    // n-strip 0..3 (48 cols)
    int m0   = blockIdx.x * 64;

    const float*  xf  = (const float*)xv;
    const ushort* xb  = (const ushort*)xv;
    ushort*       Afb = (ushort*)Af;     // bf16 path aliases the A buffer

    // Per step frags: B f=nt*2+ks (24 x 1KB); A f32 a=(amt*2+ks)*2+hf
    // (16 x 1KB); A bf16 a=amt*2+ks (8 x 1KB).
    auto stage = [&](int buf, int kkk) {
        if (F32M) {
            if (w < 8) {                 // 2 B + 1 A  (3 DMAs)
                #pragma unroll
                for (int j = 0; j < 2; ++j) {
                    int f  = w * 2 + j;  // 0..15
                    int nt = f >> 1, ks = f & 1;
                    gl_lds16(Wt + (size_t)(nt * 16 + col) * DD + kkk + ks * 32 + quad * 8,
                             Bf + ((size_t)buf * 24 + f) * 512);
                }
                int a = w;               // 0..7
                gl_lds16(xf + (size_t)(m0 + (a >> 2) * 16 + col) * DD
                             + kkk + ((a >> 1) & 1) * 32 + (a & 1) * 4 + quad * 8,
                         Af + ((size_t)buf * 16 + a) * 256);
            } else {                     // 1 B + 1 A  (2 DMAs)
                int f  = 16 + (w - 8);   // 16..23
                int nt = f >> 1, ks = f & 1;
                gl_lds16(Wt + (size_t)(nt * 16 + col) * DD + kkk + ks * 32 + quad * 8,
                         Bf + ((size_t)buf * 24 + f) * 512);
                int a = w;               // 8..15
                gl_lds16(xf + (size_t)(m0 + (a >> 2) * 16 + col) * DD
                             + kkk + ((a >> 1) & 1) * 32 + (a & 1) * 4 + quad * 8,
                         Af + ((size_t)buf * 16 + a) * 256);
            }
        } else {
            if (w < 12) {                // 2 B
                #pragma unroll
                for (int j = 0; j < 2; ++j) {
                    int f  = w * 2 + j;  // 0..23
                    int nt = f >> 1, ks = f & 1;
                    gl_lds16(Wt + (size_t)(nt * 16 + col) * DD + kkk + ks * 32 + quad * 8,
                             Bf + ((size_t)buf * 24 + f) * 512);
                }
            } else {                     // 2 A
                #pragma unroll
                for (int j = 0; j < 2; ++j) {
                    int a = (w - 12) * 2 + j;      // 0..7 = amt*2+ks
                    gl_lds16(xb + (size_t)(m0 + (a >> 1) * 16 + col) * DD
                                 + kkk + (a & 1) * 32 + quad * 8,
                             Afb + ((size_t)buf * 8 + a) * 512);
                }
            }
        }
    };

    f32x4 acc[3];
    #pragma unroll
    for (int i = 0; i < 3; ++i) acc[i] = (f32x4){0.f,0.f,0.f,0.f};

    stage(0, 0);
    stage(1, 64);
    for (int kk = 0; kk < DD; kk += 64) {
        int t   = kk >> 6;
        int p   = t % 3;
        int kn2 = (kk + 128 < DD) ? kk + 128 : kk;   // clamp: redundant re-stage
        stage((p + 2) % 3, kn2);                     // depth-2 prefetch
        if (F32M) {
            if (w < 8) __builtin_amdgcn_s_waitcnt(WCNT_VM6);  // own step-t done;
            else       __builtin_amdgcn_s_waitcnt(WCNT_VM4);  // t+1,t+2 in flight
        } else {
            __builtin_amdgcn_s_waitcnt(WCNT_VM4);
        }
        __builtin_amdgcn_s_barrier();

        #pragma unroll
        for (int ks = 0; ks < 2; ++ks) {
            bf16x8 a;
            if (F32M) {
                f32x4 alo = *reinterpret_cast<const f32x4*>(Af + ((size_t)p * 16 + ((mt * 2 + ks) * 2 + 0)) * 256 + lane * 4);
                f32x4 ahi = *reinterpret_cast<const f32x4*>(Af + ((size_t)p * 16 + ((mt * 2 + ks) * 2 + 1)) * 256 + lane * 4);
                #pragma unroll
                for (int j = 0; j < 4; ++j) { a[j] = (__bf16)alo[j]; a[4+j] = (__bf16)ahi[j]; }
            } else {
                a = ldb8(Afb + ((size_t)p * 8 + mt * 2 + ks) * 512 + lane * 8);
            }
            #pragma unroll
            for (int j = 0; j < 3; ++j) {
                int nt = nh * 3 + j;
                bf16x8 b = ldb8(Bf + ((size_t)p * 24 + nt * 2 + ks) * 512 + lane * 8);
                acc[j] = __builtin_amdgcn_mfma_f32_16x16x32_bf16(a, b, acc[j], 0, 0, 0);
            }
        }
        __builtin_amdgcn_s_waitcnt(WCNT_LGKM0);   // buf[p] reads complete
        __builtin_amdgcn_s_barrier();             // before buf[p] re-stage (t+1)
    }

    // C/D layout: row = quad*4 + reg, col = lane&15
    #pragma unroll
    for (int j = 0; j < 3; ++j) {
        int nt  = nh * 3 + j;
        int mat = nt >> 2;                 // 0=Q,1=K,2=V
        int h   = (nt & 3) * 16 + col;
        if (mat == 2) {
            #pragma unroll
            for (int r = 0; r < 4; ++r) {
                int row = m0 + mt * 16 + quad * 4 + r;
                int bb = row >> 11;
                int t  = row & (TT - 1);
                Vtw[(size_t)bb * HDIM * TT + (size_t)h * TT + t] = f2bf_bits(acc[j][r]);
            }
        } else {
            ushort* outp = (mat == 0) ? Qw : Kw;
            #pragma unroll
            for (int r = 0; r < 4; ++r) {
                int row = m0 + mt * 16 + quad * 4 + r;
                outp[(size_t)row * HDIM + h] = f2bf_bits(acc[j][r]);
            }
        }
    }
}

__global__ __launch_bounds__(1024) void k_proj(const void* __restrict__ xv,
                                               const ushort* __restrict__ Wt,
                                               ushort* __restrict__ Qw,
                                               ushort* __restrict__ Kw,
                                               ushort* __restrict__ Vtw) {
    __shared__ ushort Bf[3 * 24 * 512];        // 72 KB (triple buffer)
    __shared__ float  Af[3 * 16 * 256];        // 48 KB (bf16 path aliases)
    if (probe_f32((const ushort*)xv)) proj_body<1>(xv, Wt, Qw, Kw, Vtw, Bf, Af);
    else                              proj_body<0>(xv, Wt, Qw, Kw, Vtw, Bf, Af);
}

// ---------------------------------------------------------------------------
// Kernel 3: split-K causal flash attention, BLOCK-SHARED K/V staging.
// (round-0 best variant, ~40us.)  Block = (b, q-group of 4 tiles, 512-key
// chunk); 4 waves each own one q-tile, sharing one double-buffered K/V
// stream (16 KB).  2 DMAs/wave/step, vmcnt(2) across barrier.  640 blocks,
// ~21 KB LDS -> all co-resident.
// ---------------------------------------------------------------------------
__global__ __launch_bounds__(256) void k_attn(const ushort* __restrict__ Qw,
                                              const ushort* __restrict__ Kw,
                                              const ushort* __restrict__ Vtw,
                                              ushort* __restrict__ Po,
                                              float* __restrict__ Pl) {
    int w    = threadIdx.x >> 6;
    int lane = threadIdx.x & 63;
    int quad = lane >> 4;
    int col  = lane & 15;
    int bid  = blockIdx.x;               // 0..639
    int b    = bid & 7;
    int idx  = 79 - (bid >> 3);          // longer blocks earlier-ish
    int c, g;
    if (idx < 32)      { c = 0; g = idx; }
    else if (idx < 56) { c = 1; g = idx - 24; }
    else if (idx < 72) { c = 2; g = idx - 40; }
    else               { c = 3; g = idx - 48; }
    int qb = 4 * g + w;                  // this wave's q-tile
    int m0 = qb * 16;
    int Bq = (qb < 32) ? qb : (qb < 64) ? 2*qb - 32 : (qb < 96) ? 3*qb - 96 : 4*qb - 192;
    int pid = b * 320 + Bq + c;

    const ushort* Qb = Qw + (size_t)b * TT * HDIM;
    const ushort* Kb = Kw + (size_t)b * TT * HDIM;
    const ushort* Vb = Vtw + (size_t)b * HDIM * TT;

    __shared__ ushort KVb[2][8][512];          // 16 KB shared double buffer
    __shared__ __hip_bfloat16 Pls[4][16][40];  //  5 KB per-wave P roundtrip

    // wave w stages frags 2w, 2w+1 of {k0l,k0h,k1l,k1h,v0,v1,v2,v3}
    auto stageKV = [&](int buf, int s) {
        #pragma unroll
        for (int j = 0; j < 2; ++j) {
            int f = w * 2 + j;
            const ushort* gp;
            if (f < 4) {
                int half = f & 1;
                int ro   = (f >> 1) * 16;
                gp = Kb + (size_t)(s + ro + col) * HDIM + half * 32 + quad * 8;
            } else {
                int vg = f - 4;
                gp = Vb + (size_t)(vg * 16 + col) * TT + s + quad * 8;
            }
            gl_lds16(gp, &KVb[buf][f][0]);
        }
    };

    bf16x8 qf0 = ldb8(Qb + (size_t)(m0 + col) * HDIM + quad * 8);
    bf16x8 qf1 = ldb8(Qb + (size_t)(m0 + col) * HDIM + 32 + quad * 8);

    f32x4 o0 = {0.f,0.f,0.f,0.f};
    f32x4 o1 = {0.f,0.f,0.f,0.f};
    f32x4 o2 = {0.f,0.f,0.f,0.f};
    f32x4 o3 = {0.f,0.f,0.f,0.f};
    float rsum[4] = {0.f, 0.f, 0.f, 0.f};

    const int start = c * 512;
    const int end   = min(start + 512, 64 * g + 64);   // block-uniform

    stageKV(0, start);
    for (int s0 = start; s0 < end; s0 += 32) {
        int p  = ((s0 - start) >> 5) & 1;
        int sn = (s0 + 32 < end) ? s0 + 32 : s0;
        stageKV(p ^ 1, sn);
        __builtin_amdgcn_s_waitcnt(WCNT_VM2);   // own step-i DMAs done
        __builtin_amdgcn_s_barrier();           // whole buf[p] staged

        if (s0 < m0 + 16) {                     // wave-uniform causal skip
            bf16x8 ck0l = ldb8(&KVb[p][0][lane * 8]);
            bf16x8 ck0h = ldb8(&KVb[p][1][lane * 8]);
            bf16x8 ck1l = ldb8(&KVb[p][2][lane * 8]);
            bf16x8 ck1h = ldb8(&KVb[p][3][lane * 8]);

            f32x4 S0 = {0.f,0.f,0.f,0.f};
            f32x4 S1 = {0.f,0.f,0.f,0.f};
            S0 = __builtin_amdgcn_mfma_f32_16x16x32_bf16(qf0, ck0l, S0, 0, 0, 0);
            S0 = __builtin_amdgcn_mfma_f32_16x16x32_bf16(qf1, ck0h, S0, 0, 0, 0);
            S1 = __builtin_amdgcn_mfma_f32_16x16x32_bf16(qf0, ck1l, S1, 0, 0, 0);
            S1 = __builtin_amdgcn_mfma_f32_16x16x32_bf16(qf1, ck1h, S1, 0, 0, 0);

            #pragma unroll
            for (int r = 0; r < 4; ++r) {
                int trow = m0 + quad * 4 + r;
                float aa = (s0 + col      > trow) ? -1e30f : S0[r];
                float dd = (s0 + 16 + col > trow) ? -1e30f : S1[r];
                float p0 = exp2f(aa);
                float p1 = exp2f(dd);
                rsum[r] += p0 + p1;
                Pls[w][quad * 4 + r][col]      = __float2bfloat16(p0);
                Pls[w][quad * 4 + r][16 + col] = __float2bfloat16(p1);
            }
            bf16x8 pf = *reinterpret_cast<const bf16x8*>(&Pls[w][col][quad * 8]);

            bf16x8 cv0 = ldb8(&KVb[p][4][lane * 8]);
            bf16x8 cv1 = ldb8(&KVb[p][5][lane * 8]);
            bf16x8 cv2 = ldb8(&KVb[p][6][lane * 8]);
            bf16x8 cv3 = ldb8(&KVb[p][7][lane * 8]);
            o0 = __builtin_amdgcn_mfma_f32_16x16x32_bf16(pf, cv0, o0, 0, 0, 0);
            o1 = __builtin_amdgcn_mfma_f32_16x16x32_bf16(pf, cv1, o1, 0, 0, 0);
            o2 = __builtin_amdgcn_mfma_f32_16x16x32_bf16(pf, cv2, o2, 0, 0, 0);
            o3 = __builtin_amdgcn_mfma_f32_16x16x32_bf16(pf, cv3, o3, 0, 0, 0);
        }
        __builtin_amdgcn_s_waitcnt(WCNT_LGKM0); // buf[p] reads complete
        __builtin_amdgcn_s_barrier();           // before buf[p] re-stage
    }

    #pragma unroll
    for (int off = 1; off < 16; off <<= 1) {
        #pragma unroll
        for (int r = 0; r < 4; ++r)
            rsum[r] += __shfl_xor(rsum[r], off, 64);
    }

    ushort* pb = Po + (size_t)pid * 1024;
    #pragma unroll
    for (int r = 0; r < 4; ++r) {
        int row = quad * 4 + r;
        pb[row * 64 + 0*16 + col] = f2bf_bits(o0[r]);
        pb[row * 64 + 1*16 + col] = f2bf_bits(o1[r]);
        pb[row * 64 + 2*16 + col] = f2bf_bits(o2[r]);
        pb[row * 64 + 3*16 + col] = f2bf_bits(o3[r]);
        if (col == 0) Pl[pid * 16 + row] = rsum[r];
    }
}

// ---------------------------------------------------------------------------
// Kernel 4: merge <=4 chunk partials (plain sum, shared implicit max=0),
// normalize by total L, store out.  One wave per (b,qb).
// ---------------------------------------------------------------------------
__global__ __launch_bounds__(256) void k_merge(const ushort* __restrict__ x,
                                               const ushort* __restrict__ Po,
                                               const float* __restrict__ Pl,
                                               void* __restrict__ outv) {
    int f32m = probe_f32(x);
    int wid  = blockIdx.x * 4 + (threadIdx.x >> 6);  // 0..1023
    int lane = threadIdx.x & 63;
    int row  = lane >> 2;
    int g    = lane & 3;
    int b    = wid >> 7;
    int qb   = wid & 127;
    int nch  = (qb >> 5) + 1;
    int Bq   = (qb < 32) ? qb : (qb < 64) ? 2*qb - 32 : (qb < 96) ? 3*qb - 96 : 4*qb - 192;
    int pid0 = b * 320 + Bq;

    float L = 0.f;
    #pragma unroll
    for (int c = 0; c < 4; ++c)
        if (c < nch) L += Pl[(pid0 + c) * 16 + row];
    float inv = 1.0f / L;

    float o[16];
    #pragma unroll
    for (int j = 0; j < 16; ++j) o[j] = 0.f;
    #pragma unroll
    for (int c = 0; c < 4; ++c) {
        if (c < nch) {
            const ushort* p = Po + (size_t)(pid0 + c) * 1024 + row * 64 + g * 16;
            bf16x8 v0 = ldb8(p);
            bf16x8 v1 = ldb8(p + 8);
            #pragma unroll
            for (int j = 0; j < 8; ++j) {
                o[j]     += (float)v0[j];
                o[8 + j] += (float)v1[j];
            }
        }
    }

    size_t obase = ((size_t)b * TT + qb * 16 + row) * HDIM + g * 16;
    if (f32m) {
        float* ob = (float*)outv + obase;
        #pragma unroll
        for (int j = 0; j < 16; ++j) ob[j] = o[j] * inv;
    } else {
        ushort* ob = (ushort*)outv + obase;
        #pragma unroll
        for (int j = 0; j < 16; ++j) ob[j] = f2bf_bits(o[j] * inv);
    }
}

// ---------------------------------------------------------------------------
extern "C" void kernel_launch(void* const* d_in, const int* in_sizes, int n_in,
                              void* d_out, int out_size, void* d_ws, size_t ws_size,
                              hipStream_t stream) {
    const ushort* x = (const ushort*)d_in[0];
    ushort* Wt  = (ushort*)d_ws;                       // 196608 elts
    ushort* Qw  = Wt + 3 * HDIM * DD;
    ushort* Kw  = Qw + (size_t)NB * TT * HDIM;
    ushort* Vtw = Kw + (size_t)NB * TT * HDIM;
    ushort* Po  = Vtw + (size_t)NB * TT * HDIM;        // 2560*1024 ushorts
    float*  Pl  = (float*)(Po + (size_t)2560 * 1024);  // ~12.2 MB total

    k_wt   <<<768, 256, 0, stream>>>(x, d_in[1], d_in[2], d_in[3], Wt);
    k_proj <<<256, 1024, 0, stream>>>(d_in[0], Wt, Qw, Kw, Vtw);
    k_attn <<<640, 256, 0, stream>>>(Qw, Kw, Vtw, Po, Pl);
    k_merge<<<256, 256, 0, stream>>>(x, Po, Pl, d_out);
}

// Round 6
// 144.575 us; speedup vs baseline: 1.2445x; 1.0605x over previous
//
#include <hip/hip_runtime.h>
#include <hip/hip_bf16.h>
#include <stdint.h>

#define NB 8
#define TT 2048
#define DD 1024
#define HDIM 64

typedef __bf16 bf16x8 __attribute__((ext_vector_type(8)));
typedef float f32x4 __attribute__((ext_vector_type(4)));
typedef ushort u16x4 __attribute__((ext_vector_type(4)));

static_assert(sizeof(bf16x8) == 16, "bf16x8 must be 16 bytes");

__device__ inline ushort f2bf_bits(float f) {
    __hip_bfloat16 h = __float2bfloat16(f);
    return *reinterpret_cast<ushort*>(&h);
}
__device__ inline float bfbits2f(ushort u) {
    unsigned v = ((unsigned)u) << 16;
    return __builtin_bit_cast(float, v);
}
__device__ inline bf16x8 ldb8(const ushort* p) {
    return *reinterpret_cast<const bf16x8*>(p);
}

// async global->LDS DMA, 16B/lane: dest = wave-uniform base + lane*16,
// source = per-lane address.
typedef __attribute__((address_space(3))) uint32_t lds_u32;
typedef const __attribute__((address_space(1))) uint32_t glb_u32;
__device__ inline void gl_lds16(const void* g, void* l) {
    __builtin_amdgcn_global_load_lds((glb_u32*)g, (lds_u32*)l, 16, 0, 0);
}

// s_waitcnt immediates (gfx9: vm[3:0]+[15:14], exp[6:4], lgkm[11:8])
#define WCNT_VM2   0xF72   // vmcnt(2)
#define WCNT_VM3   0xF73   // vmcnt(3)
#define WCNT_VM5   0xF75   // vmcnt(5)
#define WCNT_LGKM0 0xC07F  // lgkmcnt(0), vmcnt/expcnt unconstrained

// ---------------------------------------------------------------------------
// Inline dtype probe: f32 x -> even halfwords show wild bf16 exponents.
// ---------------------------------------------------------------------------
__device__ inline int probe_f32(const ushort* x) {
    int lane = threadIdx.x & 63;
    int wild = 0;
    #pragma unroll
    for (int j = 0; j < 4; ++j) {
        ushort u = x[(lane * 4 + j) * 32];
        int e = (u >> 7) & 0xFF;
        wild += (e >= 0xC0);
    }
    unsigned long long m = __ballot(wild > 0);
    return __popcll(m) > 8;
}

// ---------------------------------------------------------------------------
// Kernel 1: pack weights -> Wt in DMA-READY layout: 16 k-steps x 24 frags x
// 1KB.  Frag f = nt*2+ks of step kk holds, at lane l=(quad,col), elements
// W[d = kk*64+ks*32+quad*8+e][n = nt*16+col] for e=0..7 -> each k_proj
// B-DMA reads a CONTIGUOUS 1KB block (16 consecutive 64B lines).
// Softmax scale * log2(e) folded into Wq (exp2 domain).
// ---------------------------------------------------------------------------
__global__ __launch_bounds__(256) void k_wt(const ushort* __restrict__ x,
                                            const void* __restrict__ Wq,
                                            const void* __restrict__ Wk,
                                            const void* __restrict__ Wv,
                                            ushort* __restrict__ Wt) {
    int f32m = probe_f32(x);
    int idx = blockIdx.x * 256 + threadIdx.x;   // 0 .. 196607
    int mat = idx >> 16;
    int rem = idx & 65535;                      // = d*64 + h
    int d = rem >> 6;
    int h = rem & 63;
    const void* W = (mat == 0) ? Wq : (mat == 1) ? Wk : Wv;
    float v;
    if (f32m) v = ((const float*)W)[rem];
    else      v = bfbits2f(((const ushort*)W)[rem]);
    if (mat == 0) v *= 0.18033688011112042f;    // 0.125 * log2(e)
    int n    = mat * 64 + h;                    // global out-col 0..191
    int nt   = n >> 4, ncol = n & 15;
    int kk   = d >> 6, ks = (d >> 5) & 1, qd = (d >> 3) & 3, e = d & 7;
    int f    = nt * 2 + ks;                     // 0..23
    Wt[((size_t)(kk * 24 + f)) * 512 + (qd * 16 + ncol) * 8 + e] = f2bf_bits(v);
}

// ---------------------------------------------------------------------------
// Kernel 2: QKV projection.  256 blocks x 1024 threads (16 waves = 4mt x
// 4nh); block = 64 rows x ALL 192 cols; wave = 16x48, 3 accs, 6 MFMA/step.
// B: 24 CONTIGUOUS 1KB DMAs/block-step from packed Wt (waves 0-7: 2,
// waves 8-15: 1), triple-buffered depth-2, counted vmcnt.
// A: per-lane ordinary global load (f32x4 / bf16x4) -> cvt -> ds_write_b64
// directly in MFMA-fragment layout, double-buffered; load issued at top of
// iter (BEFORE stageB so its dependency-wait doesn't drain the B pipe),
// written after compute.  DMAs/CU: 640 -> 384.  LDS 88 KB.
// ---------------------------------------------------------------------------
template <int F32M>
__device__ inline void proj_body(const void* __restrict__ xv,
                                 const ushort* __restrict__ Wt,
                                 ushort* __restrict__ Qw,
                                 ushort* __restrict__ Kw,
                                 ushort* __restrict__ Vtw,
                                 ushort* Bf, ushort* Afb) {
    int tid  = threadIdx.x;
    int w    = tid >> 6;                 // 0..15
    int lane = tid & 63;
    int quad = lane >> 4;
    int col  = lane & 15;
    int mt   = w >> 2;                   // m-tile 0..3
    int nh   = w & 3;                    // n-strip 0..3 (48 cols)
    int m0   = blockIdx.x * 64;

    const float*  xf = (const float*)xv;
    const ushort* xb = (const ushort*)xv;

    // B staging: contiguous 1KB frags.
    auto stageB = [&](int buf, int kkk) {
        int kk24 = (kkk >> 6) * 24;
        if (w < 8) {
            #pragma unroll
            for (int j = 0; j < 2; ++j) {
                int f = w * 2 + j;       // 0..15
                gl_lds16(Wt + ((size_t)(kk24 + f)) * 512 + lane * 8,
                         Bf + ((size_t)buf * 24 + f) * 512);
            }
        } else {
            int f = 16 + (w - 8);        // 16..23
            gl_lds16(Wt + ((size_t)(kk24 + f)) * 512 + lane * 8,
                     Bf + ((size_t)buf * 24 + f) * 512);
        }
    };

    // A: this lane owns x[row = m0 + w*4 + quad][kkk + col*4 .. +3].
    // Fragment-layout dest (frag a = amt*2+ks; elem l'*8+e: row=amt*16+
    // (l'&15), k = ks*32 + (l'>>4)*8 + e):
    int arow = m0 + w * 4 + quad;
    int aa   = (w >> 2) * 2 + (col >> 3);                    // frag index
    int aoff = (((col & 7) >> 1) * 16 + (w & 3) * 4 + quad) * 8
             + (col & 1) * 4;                                // ushort offset

    f32x4 ar_f;
    u16x4 ar_b;
    auto loadA = [&](int kkk) {
        if (F32M) ar_f = *reinterpret_cast<const f32x4*>(xf + (size_t)arow * DD + kkk + col * 4);
        else      ar_b = *reinterpret_cast<const u16x4*>(xb + (size_t)arow * DD + kkk + col * 4);
    };
    auto writeA = [&](int q) {
        u16x4 v;
        if (F32M) {
            #pragma unroll
            for (int j = 0; j < 4; ++j) v[j] = f2bf_bits(ar_f[j]);
        } else {
            v = ar_b;
        }
        *reinterpret_cast<u16x4*>(Afb + ((size_t)q * 8 + aa) * 512 + aoff) = v;
    };

    f32x4 acc[3];
    #pragma unroll
    for (int i = 0; i < 3; ++i) acc[i] = (f32x4){0.f,0.f,0.f,0.f};

    // prologue: A_0 load first (oldest vmem -> its wait keeps B in flight)
    loadA(0);
    stageB(0, 0);
    stageB(1, 64);
    writeA(0);
    __builtin_amdgcn_s_waitcnt(WCNT_LGKM0);   // A_0 ds_write landed

    for (int t = 0; t < 16; ++t) {
        int p   = t % 3;                       // B buffer holding B_t
        int p2  = (t + 2) % 3;
        int kn1 = (t + 1 < 16) ? (t + 1) * 64 : 960;
        int kn2 = (t + 2 < 16) ? (t + 2) * 64 : 960;
        loadA(kn1);                            // A_{t+1} -> regs (issued first)
        stageB(p2, kn2);                       // B_{t+2} depth-2 prefetch
        // retire own B_t DMAs; keep B_{t+1}, B_{t+2}, A_{t+1} in flight
        if (w < 8) __builtin_amdgcn_s_waitcnt(WCNT_VM5);
        else       __builtin_amdgcn_s_waitcnt(WCNT_VM3);
        __builtin_amdgcn_s_barrier();          // B_t + A_t visible block-wide

        int q = t & 1;
        #pragma unroll
        for (int ks = 0; ks < 2; ++ks) {
            bf16x8 a = ldb8(Afb + ((size_t)q * 8 + mt * 2 + ks) * 512 + lane * 8);
            #pragma unroll
            for (int j = 0; j < 3; ++j) {
                int nt = nh * 3 + j;
                bf16x8 b = ldb8(Bf + ((size_t)p * 24 + nt * 2 + ks) * 512 + lane * 8);
                acc[j] = __builtin_amdgcn_mfma_f32_16x16x32_bf16(a, b, acc[j], 0, 0, 0);
            }
        }
        writeA(q ^ 1);                         // A_{t+1} into other buffer
        __builtin_amdgcn_s_waitcnt(WCNT_LGKM0);
        __builtin_amdgcn_s_barrier();          // reads done; write visible
    }

    // C/D layout: row = quad*4 + reg, col = lane&15
    #pragma unroll
    for (int j = 0; j < 3; ++j) {
        int nt  = nh * 3 + j;
        int mat = nt >> 2;                 // 0=Q,1=K,2=V
        int h   = (nt & 3) * 16 + col;
        if (mat == 2) {
            #pragma unroll
            for (int r = 0; r < 4; ++r) {
                int row = m0 + mt * 16 + quad * 4 + r;
                int bb = row >> 11;
                int t  = row & (TT - 1);
                Vtw[(size_t)bb * HDIM * TT + (size_t)h * TT + t] = f2bf_bits(acc[j][r]);
            }
        } else {
            ushort* outp = (mat == 0) ? Qw : Kw;
            #pragma unroll
            for (int r = 0; r < 4; ++r) {
                int row = m0 + mt * 16 + quad * 4 + r;
                outp[(size_t)row * HDIM + h] = f2bf_bits(acc[j][r]);
            }
        }
    }
}

__global__ __launch_bounds__(1024) void k_proj(const void* __restrict__ xv,
                                               const ushort* __restrict__ Wt,
                                               ushort* __restrict__ Qw,
                                               ushort* __restrict__ Kw,
                                               ushort* __restrict__ Vtw) {
    __shared__ ushort Bf[3 * 24 * 512];        // 72 KB (triple buffer)
    __shared__ ushort Afb[2 * 8 * 512];        // 16 KB (double buffer)
    if (probe_f32((const ushort*)xv)) proj_body<1>(xv, Wt, Qw, Kw, Vtw, Bf, Afb);
    else                              proj_body<0>(xv, Wt, Qw, Kw, Vtw, Bf, Afb);
}

// ---------------------------------------------------------------------------
// Kernel 3: split-K causal flash attention, BLOCK-SHARED K/V staging.
// (round-0 best variant, ~40us.)  Block = (b, q-group of 4 tiles, 512-key
// chunk); 4 waves each own one q-tile, sharing one double-buffered K/V
// stream (16 KB).  2 DMAs/wave/step, vmcnt(2) across barrier.  640 blocks,
// ~21 KB LDS -> all co-resident.
// ---------------------------------------------------------------------------
__global__ __launch_bounds__(256) void k_attn(const ushort* __restrict__ Qw,
                                              const ushort* __restrict__ Kw,
                                              const ushort* __restrict__ Vtw,
                                              ushort* __restrict__ Po,
                                              float* __restrict__ Pl) {
    int w    = threadIdx.x >> 6;
    int lane = threadIdx.x & 63;
    int quad = lane >> 4;
    int col  = lane & 15;
    int bid  = blockIdx.x;               // 0..639
    int b    = bid & 7;
    int idx  = 79 - (bid >> 3);          // longer blocks earlier-ish
    int c, g;
    if (idx < 32)      { c = 0; g = idx; }
    else if (idx < 56) { c = 1; g = idx - 24; }
    else if (idx < 72) { c = 2; g = idx - 40; }
    else               { c = 3; g = idx - 48; }
    int qb = 4 * g + w;                  // this wave's q-tile
    int m0 = qb * 16;
    int Bq = (qb < 32) ? qb : (qb < 64) ? 2*qb - 32 : (qb < 96) ? 3*qb - 96 : 4*qb - 192;
    int pid = b * 320 + Bq + c;

    const ushort* Qb = Qw + (size_t)b * TT * HDIM;
    const ushort* Kb = Kw + (size_t)b * TT * HDIM;
    const ushort* Vb = Vtw + (size_t)b * HDIM * TT;

    __shared__ ushort KVb[2][8][512];          // 16 KB shared double buffer
    __shared__ __hip_bfloat16 Pls[4][16][40];  //  5 KB per-wave P roundtrip

    // wave w stages frags 2w, 2w+1 of {k0l,k0h,k1l,k1h,v0,v1,v2,v3}
    auto stageKV = [&](int buf, int s) {
        #pragma unroll
        for (int j = 0; j < 2; ++j) {
            int f = w * 2 + j;
            const ushort* gp;
            if (f < 4) {
                int half = f & 1;
                int ro   = (f >> 1) * 16;
                gp = Kb + (size_t)(s + ro + col) * HDIM + half * 32 + quad * 8;
            } else {
                int vg = f - 4;
                gp = Vb + (size_t)(vg * 16 + col) * TT + s + quad * 8;
            }
            gl_lds16(gp, &KVb[buf][f][0]);
        }
    };

    bf16x8 qf0 = ldb8(Qb + (size_t)(m0 + col) * HDIM + quad * 8);
    bf16x8 qf1 = ldb8(Qb + (size_t)(m0 + col) * HDIM + 32 + quad * 8);

    f32x4 o0 = {0.f,0.f,0.f,0.f};
    f32x4 o1 = {0.f,0.f,0.f,0.f};
    f32x4 o2 = {0.f,0.f,0.f,0.f};
    f32x4 o3 = {0.f,0.f,0.f,0.f};
    float rsum[4] = {0.f, 0.f, 0.f, 0.f};

    const int start = c * 512;
    const int end   = min(start + 512, 64 * g + 64);   // block-uniform

    stageKV(0, start);
    for (int s0 = start; s0 < end; s0 += 32) {
        int p  = ((s0 - start) >> 5) & 1;
        int sn = (s0 + 32 < end) ? s0 + 32 : s0;
        stageKV(p ^ 1, sn);
        __builtin_amdgcn_s_waitcnt(WCNT_VM2);   // own step-i DMAs done
        __builtin_amdgcn_s_barrier();           // whole buf[p] staged

        if (s0 < m0 + 16) {                     // wave-uniform causal skip
            bf16x8 ck0l = ldb8(&KVb[p][0][lane * 8]);
            bf16x8 ck0h = ldb8(&KVb[p][1][lane * 8]);
            bf16x8 ck1l = ldb8(&KVb[p][2][lane * 8]);
            bf16x8 ck1h = ldb8(&KVb[p][3][lane * 8]);

            f32x4 S0 = {0.f,0.f,0.f,0.f};
            f32x4 S1 = {0.f,0.f,0.f,0.f};
            S0 = __builtin_amdgcn_mfma_f32_16x16x32_bf16(qf0, ck0l, S0, 0, 0, 0);
            S0 = __builtin_amdgcn_mfma_f32_16x16x32_bf16(qf1, ck0h, S0, 0, 0, 0);
            S1 = __builtin_amdgcn_mfma_f32_16x16x32_bf16(qf0, ck1l, S1, 0, 0, 0);
            S1 = __builtin_amdgcn_mfma_f32_16x16x32_bf16(qf1, ck1h, S1, 0, 0, 0);

            #pragma unroll
            for (int r = 0; r < 4; ++r) {
                int trow = m0 + quad * 4 + r;
                float aa = (s0 + col      > trow) ? -1e30f : S0[r];
                float dd = (s0 + 16 + col > trow) ? -1e30f : S1[r];
                float p0 = exp2f(aa);
                float p1 = exp2f(dd);
                rsum[r] += p0 + p1;
                Pls[w][quad * 4 + r][col]      = __float2bfloat16(p0);
                Pls[w][quad * 4 + r][16 + col] = __float2bfloat16(p1);
            }
            bf16x8 pf = *reinterpret_cast<const bf16x8*>(&Pls[w][col][quad * 8]);

            bf16x8 cv0 = ldb8(&KVb[p][4][lane * 8]);
            bf16x8 cv1 = ldb8(&KVb[p][5][lane * 8]);
            bf16x8 cv2 = ldb8(&KVb[p][6][lane * 8]);
            bf16x8 cv3 = ldb8(&KVb[p][7][lane * 8]);
            o0 = __builtin_amdgcn_mfma_f32_16x16x32_bf16(pf, cv0, o0, 0, 0, 0);
            o1 = __builtin_amdgcn_mfma_f32_16x16x32_bf16(pf, cv1, o1, 0, 0, 0);
            o2 = __builtin_amdgcn_mfma_f32_16x16x32_bf16(pf, cv2, o2, 0, 0, 0);
            o3 = __builtin_amdgcn_mfma_f32_16x16x32_bf16(pf, cv3, o3, 0, 0, 0);
        }
        __builtin_amdgcn_s_waitcnt(WCNT_LGKM0); // buf[p] reads complete
        __builtin_amdgcn_s_barrier();           // before buf[p] re-stage
    }

    #pragma unroll
    for (int off = 1; off < 16; off <<= 1) {
        #pragma unroll
        for (int r = 0; r < 4; ++r)
            rsum[r] += __shfl_xor(rsum[r], off, 64);
    }

    ushort* pb = Po + (size_t)pid * 1024;
    #pragma unroll
    for (int r = 0; r < 4; ++r) {
        int row = quad * 4 + r;
        pb[row * 64 + 0*16 + col] = f2bf_bits(o0[r]);
        pb[row * 64 + 1*16 + col] = f2bf_bits(o1[r]);
        pb[row * 64 + 2*16 + col] = f2bf_bits(o2[r]);
        pb[row * 64 + 3*16 + col] = f2bf_bits(o3[r]);
        if (col == 0) Pl[pid * 16 + row] = rsum[r];
    }
}

// ---------------------------------------------------------------------------
// Kernel 4: merge <=4 chunk partials (plain sum, shared implicit max=0),
// normalize by total L, store out.  One wave per (b,qb).
// ---------------------------------------------------------------------------
__global__ __launch_bounds__(256) void k_merge(const ushort* __restrict__ x,
                                               const ushort* __restrict__ Po,
                                               const float* __restrict__ Pl,
                                               void* __restrict__ outv) {
    int f32m = probe_f32(x);
    int wid  = blockIdx.x * 4 + (threadIdx.x >> 6);  // 0..1023
    int lane = threadIdx.x & 63;
    int row  = lane >> 2;
    int g    = lane & 3;
    int b    = wid >> 7;
    int qb   = wid & 127;
    int nch  = (qb >> 5) + 1;
    int Bq   = (qb < 32) ? qb : (qb < 64) ? 2*qb - 32 : (qb < 96) ? 3*qb - 96 : 4*qb - 192;
    int pid0 = b * 320 + Bq;

    float L = 0.f;
    #pragma unroll
    for (int c = 0; c < 4; ++c)
        if (c < nch) L += Pl[(pid0 + c) * 16 + row];
    float inv = 1.0f / L;

    float o[16];
    #pragma unroll
    for (int j = 0; j < 16; ++j) o[j] = 0.f;
    #pragma unroll
    for (int c = 0; c < 4; ++c) {
        if (c < nch) {
            const ushort* p = Po + (size_t)(pid0 + c) * 1024 + row * 64 + g * 16;
            bf16x8 v0 = ldb8(p);
            bf16x8 v1 = ldb8(p + 8);
            #pragma unroll
            for (int j = 0; j < 8; ++j) {
                o[j]     += (float)v0[j];
                o[8 + j] += (float)v1[j];
            }
        }
    }

    size_t obase = ((size_t)b * TT + qb * 16 + row) * HDIM + g * 16;
    if (f32m) {
        float* ob = (float*)outv + obase;
        #pragma unroll
        for (int j = 0; j < 16; ++j) ob[j] = o[j] * inv;
    } else {
        ushort* ob = (ushort*)outv + obase;
        #pragma unroll
        for (int j = 0; j < 16; ++j) ob[j] = f2bf_bits(o[j] * inv);
    }
}

// ---------------------------------------------------------------------------
extern "C" void kernel_launch(void* const* d_in, const int* in_sizes, int n_in,
                              void* d_out, int out_size, void* d_ws, size_t ws_size,
                              hipStream_t stream) {
    const ushort* x = (const ushort*)d_in[0];
    ushort* Wt  = (ushort*)d_ws;                       // 196608 elts
    ushort* Qw  = Wt + 3 * HDIM * DD;
    ushort* Kw  = Qw + (size_t)NB * TT * HDIM;
    ushort* Vtw = Kw + (size_t)NB * TT * HDIM;
    ushort* Po  = Vtw + (size_t)NB * TT * HDIM;        // 2560*1024 ushorts
    float*  Pl  = (float*)(Po + (size_t)2560 * 1024);  // ~12.2 MB total

    k_wt   <<<768, 256, 0, stream>>>(x, d_in[1], d_in[2], d_in[3], Wt);
    k_proj <<<256, 1024, 0, stream>>>(d_in[0], Wt, Qw, Kw, Vtw);
    k_attn <<<640, 256, 0, stream>>>(Qw, Kw, Vtw, Po, Pl);
    k_merge<<<256, 256, 0, stream>>>(x, Po, Pl, d_out);
}